// Round 1
// 123.951 us; speedup vs baseline: 1.0307x; 1.0307x over previous
//
#include <hip/hip_runtime.h>
#include <math.h>

#define N_G 512
#define IMG_H 324
#define IMG_W 332
#define N_C 120
#define HW (IMG_H*IMG_W)
#define CHUNK 64
#define TSX 21                 // tiles in x (16 px)
#define TSY 81                 // tiles in y (4 px)
#define NT (TSX*TSY)
#define NBLK 512               // 2 persistent blocks per CU (LDS-capped)

// Single fused kernel. Each block:
//   startup: project its 2-gaussians-per-thread into REGISTERS (bbox, cov, op, depth)
//   per tile (static center-out interleave t = bid, bid+512, ...):
//     build: ballot-compact hits -> depth keys in LDS -> per-hit rank-scan
//            (stable by (depth, original index), matching the reference argsort)
//            -> write prm row at rank (sorted, no global pre-pass needed)
//     chunks of 64 hits:
//       1a: araw[j][px] + stage spec row j -> sbuf (4 waves, pipelined)
//       1b: wave0 per-pixel cumprod (araw -> w in place)
//       2 : acc[px][c] += w[j][px]*sbuf[j][c]   (broadcast b128 reads)
//     epilogue: combine hit-parity partials, store 122 channels

#define ACC4(i) \
  { float4 s4 = *(const float4*)(row + 4*(i)); \
    a##i.x = fmaf(wv, s4.x, a##i.x); \
    a##i.y = fmaf(wv, s4.y, a##i.y); \
    a##i.z = fmaf(wv, s4.z, a##i.z); \
    a##i.w = fmaf(wv, s4.w, a##i.w); }

#define WR4(i) \
  { slot[4*(i)+0]=a##i.x; slot[4*(i)+1]=a##i.y; \
    slot[4*(i)+2]=a##i.z; slot[4*(i)+3]=a##i.w; }

#define CMB4(i) \
  { float4 t4 = *(const float4*)(tmh + 4*(i)); \
    out[(cbase + 4*(i) + 0)*HW + pixi] = (a##i.x + slot[4*(i)+0] + bgT)*t4.x; \
    out[(cbase + 4*(i) + 1)*HW + pixi] = (a##i.y + slot[4*(i)+1] + bgT)*t4.y; \
    out[(cbase + 4*(i) + 2)*HW + pixi] = (a##i.z + slot[4*(i)+2] + bgT)*t4.z; \
    out[(cbase + 4*(i) + 3)*HW + pixi] = (a##i.w + slot[4*(i)+3] + bgT)*t4.w; }

__global__ __launch_bounds__(256, 2) void k_render(
    const float* __restrict__ pos, const float* __restrict__ scales,
    const float* __restrict__ opac, const float* __restrict__ Km,
    const float* __restrict__ Em, const float* __restrict__ spec,
    const float* __restrict__ tm, float* __restrict__ out)
{
  __shared__ float prm[N_G*8];          // rank-sorted hit params (16 KB)
  __shared__ float buf[CHUNK*64];       // keys during build; araw->w in chunks (16 KB)
  __shared__ float sbuf[CHUNK*N_C];     // staged spectral rows (30.7 KB)
  __shared__ float Tcar[64], Dcar[64];
  __shared__ int wcnt[4];

  const int tid  = threadIdx.x;
  const int w    = tid >> 6;
  const int lane = tid & 63;
  const int h    = w & 1;               // channel half
  const int s    = w >> 1;              // hit parity
  const int tx = lane & 15, ty = lane >> 4;
  const int cbase = h*60;
  const unsigned long long ltm = (1ull << lane) - 1ull;

  // ---- hoisted prep: project 2 gaussians per thread into registers ----
  float psx[2], psy[2], pc00[2], pc11[2], pl2[2], pd[2];
  float bxmin[2], bxmax[2], bymin[2], bymax[2];
  {
    const float E0=Em[0],E1=Em[1],E2=Em[2],E3=Em[3],
                E4=Em[4],E5=Em[5],E6=Em[6],E7=Em[7],
                E8=Em[8],E9=Em[9],E10=Em[10],E11=Em[11];
    const float K0=Km[0],K1=Km[1],K2=Km[2],
                K3=Km[3],K4=Km[4],K5=Km[5],
                K6=Km[6],K7=Km[7],K8=Km[8];
    #pragma unroll
    for (int q = 0; q < 2; ++q) {
      const int g = w*128 + lane + q*64;           // original index (wave-major)
      float p0 = pos[g*3+0], p1 = pos[g*3+1], p2 = pos[g*3+2];
      float cam0 = E0*p0 + E1*p1 + E2*p2  + E3;
      float cam1 = E4*p0 + E5*p1 + E6*p2  + E7;
      float cam2 = E8*p0 + E9*p1 + E10*p2 + E11;
      float pr0 = K0*cam0 + K1*cam1 + K2*cam2;
      float pr1 = K3*cam0 + K4*cam1 + K5*cam2;
      float pr2 = K6*cam0 + K7*cam1 + K8*cam2;
      float inv = 1.0f/(pr2 + 1e-6f);
      float sx = pr0*inv, sy = pr1*inv;
      float depth = cam2;
      bool valid = (depth > 0.01f) && (depth < 100.0f)
                && (sx > -100.0f) && (sx < (float)IMG_W + 100.0f)
                && (sy > -100.0f) && (sy < (float)IMG_H + 100.0f);
      bool off = (sx < -(float)IMG_W) || (sx > 2.0f*(float)IMG_W)
              || (sy < -(float)IMG_H) || (sy > 2.0f*(float)IMG_H);
      bool skip = off || (!valid);
      float s0 = scales[g*3+0], s1 = scales[g*3+1];
      float v0 = s0*s0 + 1e-4f, v1 = s1*s1 + 1e-4f;
      const float HL2E = 0.72134752f;              // 0.5*log2(e)
      psx[q] = sx; psy[q] = sy;
      pc00[q] = HL2E/v0; pc11[q] = HL2E/v1;
      pl2[q] = __log2f(skip ? 0.0f : opac[g]);     // op=0 -> -inf -> exp2 -> 0
      pd[q]  = depth;
      float rx = 6.0f*sqrtf(v0);                   // mahal cutoff 36 (6 sigma)
      float ry = 6.0f*sqrtf(v1);
      bxmin[q] = skip ?  1e9f : sx - rx;
      bxmax[q] = skip ? -1e9f : sx + rx;
      bymin[q] = skip ?  1e9f : sy - ry;
      bymax[q] = skip ? -1e9f : sy + ry;
    }
  }

  for (int t = blockIdx.x; t < NT; t += NBLK) {
    // center-out bijection: hot center tiles distributed one-per-block
    const int jx = t % TSX, ky = t / TSX;
    const int bx = 10 + ((jx & 1) ? ((jx+1)>>1) : -((jx+1)>>1));
    const int by = 40 + ((ky & 1) ? ((ky+1)>>1) : -((ky+1)>>1));

    const int x = bx*16 + tx;
    const int y = by*4 + ty;
    const bool inb = (x < IMG_W) && (y < IMG_H);
    const float px = (float)min(x, IMG_W-1);
    const float py = (float)min(y, IMG_H-1);
    const float wxmin = (float)(bx*16), wxmax = wxmin + 15.0f;
    const float wymin = (float)(by*4),  wymax = wymin + 3.0f;

    // ---- build: ballot compaction + per-tile depth rank-sort ----
    bool h0 = !(bxmin[0] > wxmax || bxmax[0] < wxmin ||
                bymin[0] > wymax || bymax[0] < wymin);
    bool h1 = !(bxmin[1] > wxmax || bxmax[1] < wxmin ||
                bymin[1] > wymax || bymax[1] < wymin);
    unsigned long long m0 = __ballot(h0), m1 = __ballot(h1);
    int c0 = __popcll(m0);
    if (lane == 0) wcnt[w] = c0 + __popcll(m1);
    __syncthreads();
    int offw = 0;
    #pragma unroll
    for (int k = 0; k < 4; ++k) if (k < w) offw += wcnt[k];
    const int nh = wcnt[0] + wcnt[1] + wcnt[2] + wcnt[3];
    // write compacted depth keys (compaction order == original-index order)
    const int p0 = offw + __popcll(m0 & ltm);
    const int p1 = offw + c0 + __popcll(m1 & ltm);
    if (h0) buf[p0] = pd[0];
    if (h1) buf[p1] = pd[1];
    if (tid < 4) buf[nh + tid] = 1e30f;            // pad for float4 scan
    __syncthreads();

    // rank-scan (broadcast b128 reads); stable tie-break by compacted position
    if (h0 | h1) {
      int r0 = 0, r1 = 0;
      const float d0 = pd[0], d1 = pd[1];
      for (int j = 0; j < nh; j += 4) {
        float4 k4 = *(const float4*)&buf[j];
        if (h0) {
          r0 += (k4.x < d0 || (k4.x == d0 && j+0 < p0)) ? 1 : 0;
          r0 += (k4.y < d0 || (k4.y == d0 && j+1 < p0)) ? 1 : 0;
          r0 += (k4.z < d0 || (k4.z == d0 && j+2 < p0)) ? 1 : 0;
          r0 += (k4.w < d0 || (k4.w == d0 && j+3 < p0)) ? 1 : 0;
        }
        if (h1) {
          r1 += (k4.x < d1 || (k4.x == d1 && j+0 < p1)) ? 1 : 0;
          r1 += (k4.y < d1 || (k4.y == d1 && j+1 < p1)) ? 1 : 0;
          r1 += (k4.z < d1 || (k4.z == d1 && j+2 < p1)) ? 1 : 0;
          r1 += (k4.w < d1 || (k4.w == d1 && j+3 < p1)) ? 1 : 0;
        }
      }
      if (h0) {
        *(float4*)&prm[r0*8]   = make_float4(psx[0], psy[0], pc00[0], pc11[0]);
        *(float4*)&prm[r0*8+4] = make_float4(pl2[0], pd[0],
                                   __int_as_float((w*128 + lane)*N_C), 0.0f);
      }
      if (h1) {
        *(float4*)&prm[r1*8]   = make_float4(psx[1], psy[1], pc00[1], pc11[1]);
        *(float4*)&prm[r1*8+4] = make_float4(pl2[1], pd[1],
                                   __int_as_float((w*128 + lane + 64)*N_C), 0.0f);
      }
    }
    __syncthreads();

    float T = 1.0f, dacc = 0.0f;        // meaningful in wave 0 (lane = pixel)
    float4 a0={0,0,0,0}, a1={0,0,0,0}, a2={0,0,0,0}, a3={0,0,0,0}, a4={0,0,0,0},
           a5={0,0,0,0}, a6={0,0,0,0}, a7={0,0,0,0}, a8={0,0,0,0}, a9={0,0,0,0},
           a10={0,0,0,0}, a11={0,0,0,0}, a12={0,0,0,0}, a13={0,0,0,0}, a14={0,0,0,0};

    for (int cb = 0; cb < nh; cb += CHUNK) {
      const int nc = min(CHUNK, nh - cb);

      // ---- phase 1a: araw + spectral-row staging (4 waves, pipelined) ----
      #pragma unroll 2
      for (int j = w; j < nc; j += 4) {
        float4 q0 = *(const float4*)&prm[(cb+j)*8];     // ds_read_b128
        float4 q1 = *(const float4*)&prm[(cb+j)*8+4];
        float dx = px - q0.x, dy = py - q0.y;
        float m = q0.z*dx*dx + q0.w*dy*dy;              // log2-units
        buf[j*64 + lane] = exp2f(q1.x - m);             // op*exp(-m/2)
        // stage spec row j: lanes = channel index (coalesced, independent)
        int sbase = __float_as_int(q1.z);               // src*120
        sbuf[j*N_C + lane] = spec[sbase + lane];
        if (lane < N_C - 64) sbuf[j*N_C + 64 + lane] = spec[sbase + 64 + lane];
      }
      __syncthreads();

      // ---- phase 1b: per-pixel cumprod (wave 0) ----
      if (w == 0) {
        #pragma unroll 4
        for (int j = 0; j < nc; ++j) {
          float a = buf[j*64 + lane];
          float wv = a * T;
          buf[j*64 + lane] = wv;
          T -= wv;
          dacc = fmaf(prm[(cb+j)*8+5], wv, dacc);
        }
      }
      __syncthreads();

      // ---- phase 2: weighted accumulation from LDS (affine addresses) ----
      #pragma unroll 2
      for (int j = s; j < nc; j += 2) {
        float wv = buf[j*64 + lane];
        const float* row = &sbuf[j*N_C + cbase];        // broadcast b128 reads
        ACC4(0)  ACC4(1)  ACC4(2)  ACC4(3)  ACC4(4)
        ACC4(5)  ACC4(6)  ACC4(7)  ACC4(8)  ACC4(9)
        ACC4(10) ACC4(11) ACC4(12) ACC4(13) ACC4(14)
      }
      __syncthreads();   // buf/sbuf reused next chunk
    }

    // ---- epilogue: combine hit-parity partials, store ----
    if (w == 0) { Tcar[lane] = T; Dcar[lane] = dacc; }
    if (s == 1) {
      // h=0 partials -> buf (64*61 <= 4096), h=1 -> sbuf
      float* slot = (h == 0 ? buf : sbuf) + lane*61;    // stride 61: conflict-free
      WR4(0)  WR4(1)  WR4(2)  WR4(3)  WR4(4)
      WR4(5)  WR4(6)  WR4(7)  WR4(8)  WR4(9)
      WR4(10) WR4(11) WR4(12) WR4(13) WR4(14)
    }
    __syncthreads();

    if (s == 0 && inb) {
      const int pixi = y*IMG_W + x;
      const float Tf = Tcar[lane];
      const float bgT = Tf;                   // BG*(1 - A_final), BG = 1.0
      const float* tmh = tm + cbase;
      const float* slot = (h == 0 ? buf : sbuf) + lane*61;
      CMB4(0)  CMB4(1)  CMB4(2)  CMB4(3)  CMB4(4)
      CMB4(5)  CMB4(6)  CMB4(7)  CMB4(8)  CMB4(9)
      CMB4(10) CMB4(11) CMB4(12) CMB4(13) CMB4(14)
      if (h == 0) out[N_C*HW + pixi] = Dcar[lane];      // depth image
      else        out[N_C*HW + HW + pixi] = 1.0f - Tf;  // A_final
    }
    __syncthreads();   // protect prm/buf/sbuf before next tile
  }
}

extern "C" void kernel_launch(void* const* d_in, const int* in_sizes, int n_in,
                              void* d_out, int out_size, void* d_ws, size_t ws_size,
                              hipStream_t stream) {
  const float* pos    = (const float*)d_in[0];
  // d_in[1] rotations: unused by the reference
  const float* scales = (const float*)d_in[2];
  const float* opac   = (const float*)d_in[3];
  const float* spec   = (const float*)d_in[4];
  const float* tm     = (const float*)d_in[5];
  const float* K      = (const float*)d_in[6];
  const float* E      = (const float*)d_in[7];
  float* out = (float*)d_out;
  (void)d_ws; (void)ws_size;   // fused kernel needs no workspace

  k_render<<<NBLK, 256, 0, stream>>>(pos, scales, opac, K, E, spec, tm, out);
}